// Round 3
// baseline (4340465.234 us; speedup 1.0000x reference)
//
#include <hip/hip_runtime.h>

// 4-layer LSTM (B=1024,T=512,H=64,G=256) + FC head.
// 256 blocks x 256 threads: block = (layer = bid&3, 16-row batch chunk) -> all 256 CUs.
// Cross-layer handoff: ring buffer in d_ws through L3 (agent-scope atomics), R slots,
// producer runs ~R-2 steps ahead; flag/ack polls are 1-step-overlapped (lane0 + shfl);
// consumer keeps a 2-step register FIFO of input fragments. All global publishes/prefetches
// are issued post-barrier so each step's __syncthreads only drains step-old traffic.
// Intra-layer recurrent h exchange via double-buffered swizzled LDS + one 4-wave barrier/step.
// bf16 MFMA 16x16x32, fp32 accum, c-state in registers. Poison-safe (0xAA.. < 0).

#define TLEN 512
#define NCH  64
#define AG   __HIP_MEMORY_SCOPE_AGENT
#define SPIN_CAP 200000

typedef __bf16 bf16x8 __attribute__((ext_vector_type(8)));
typedef float  f32x4  __attribute__((ext_vector_type(4)));

struct Params {
  const float* x;
  const float* wih[4]; const float* whh[4];
  const float* bih[4]; const float* bhh[4];
  const float* fc1w; const float* fc1b;
  const float* fc2w; const float* fc2b;
  float* out; char* ws;
  int R; int Rmask; int guard;   // ring slots, mask, reuse-guard margin
};

__device__ __forceinline__ bf16x8 bfzero() {
  union { unsigned long long u[2]; bf16x8 v; } z; z.u[0] = 0ull; z.u[1] = 0ull; return z.v;
}
__device__ __forceinline__ float fast_sigmoid(float x) {
  return __builtin_amdgcn_rcpf(1.f + __expf(-x));
}
__device__ __forceinline__ float fast_tanh(float x) {
  float e = __expf(2.f * x);
  return 1.f - 2.f * __builtin_amdgcn_rcpf(e + 1.f);
}
// ring fragment pair load (A-layout: lane&15 = row, k = 32q + quad*8 + j)
__device__ __forceinline__ void load_frag_pair(const unsigned short* sb, int l15, int quad,
                                               bf16x8& f0, bf16x8& f1) {
  const unsigned long long* a = (const unsigned long long*)(sb + l15 * 64 + quad * 8);
  const unsigned long long* b = (const unsigned long long*)(sb + l15 * 64 + 32 + quad * 8);
  union { bf16x8 v; unsigned long long u[2]; } c0, c1;
  c0.u[0] = __hip_atomic_load(&a[0], __ATOMIC_RELAXED, AG);
  c0.u[1] = __hip_atomic_load(&a[1], __ATOMIC_RELAXED, AG);
  c1.u[0] = __hip_atomic_load(&b[0], __ATOMIC_RELAXED, AG);
  c1.u[1] = __hip_atomic_load(&b[1], __ATOMIC_RELAXED, AG);
  f0 = c0.v; f1 = c1.v;
}

__global__ __launch_bounds__(256, 1) void lstm_ring(Params p)
{
  const int bid   = blockIdx.x;
  const int L     = bid & 3;
  const int chunk = bid >> 2;
  const int b0    = chunk * 16;
  const int tid   = threadIdx.x;
  const int w     = tid >> 6;
  const int lane  = tid & 63;
  const int quad  = lane >> 4;
  const int l15   = lane & 15;

  __shared__ __bf16 h_lds[2 * 16 * 64];
  __shared__ float  s_fc1w[2048];
  __shared__ float  s_z[512];
  __shared__ float  s_fc1b[32];
  __shared__ float  s_fc2w[96];
  __shared__ float  s_fc2b[3];

  int* prodflag = (int*)p.ws;                        // [(Lb*NCH+chunk)*16], 64B stride
  int* ackflag  = (int*)(p.ws + 16 * 1024);
  unsigned short* ring = (unsigned short*)(p.ws + 64 * 1024); // slot = 16x64 bf16 = 2KB
  const int R = p.R, RM = p.Rmask, GM = p.guard;

  // ---- weight fragments (bf16, registers) ----
  bf16x8 whhf[4][2], wihf[4][2];
  float  bias[4];
  {
    const float* whh = p.whh[L];
    const float* wih = p.wih[L];
    const float* bih = p.bih[L];
    const float* bhh = p.bhh[L];
#pragma unroll
    for (int g = 0; g < 4; g++) {
      int n = g * 64 + w * 16 + l15;   // B-frag: lane&15 = n, k = 32q + quad*8 + j
      bias[g] = bih[n] + bhh[n];
#pragma unroll
      for (int q = 0; q < 2; q++) {
        const float* s = whh + n * 64 + q * 32 + quad * 8;
        bf16x8 f;
#pragma unroll
        for (int j = 0; j < 8; j++) f[j] = (__bf16)s[j];
        whhf[g][q] = f;
      }
      if (L == 0) {                    // w_ih_0 is (256,4): pad K to 32 with zeros
        bf16x8 f = bfzero();
        if (quad == 0) {
#pragma unroll
          for (int j = 0; j < 4; j++) f[j] = (__bf16)wih[n * 4 + j];
        }
        wihf[g][0] = f; wihf[g][1] = f;
      } else {
#pragma unroll
        for (int q = 0; q < 2; q++) {
          const float* s = wih + n * 64 + q * 32 + quad * 8;
          bf16x8 f;
#pragma unroll
          for (int j = 0; j < 8; j++) f[j] = (__bf16)s[j];
          wihf[g][q] = f;
        }
      }
    }
  }

  { int* hi = (int*)h_lds; for (int i = tid; i < 1024; i += 256) hi[i] = 0; }
  float cst[4] = {0.f, 0.f, 0.f, 0.f};
  __syncthreads();

  const int srcf = (L > 0) ? ((L - 1) * NCH + chunk) * 16 : 0;
  const int ownf = (L * NCH + chunk) * 16;
  const size_t srcring = (L > 0) ? (size_t)((L - 1) * NCH + chunk) * R : 0;
  const size_t ownring = (size_t)(L * NCH + chunk) * R;

  // consumer register FIFO: xA = frag for step t, xB = frag for t+1
  bf16x8 xA0 = bfzero(), xA1 = bfzero(), xB0 = bfzero(), xB1 = bfzero();
  int W = 0, f_pend = 0;
  int ackW = -1000000, a_pend = -1000000;

  if (L == 0) {
    if (quad == 0) {
      const float4 x0 = *(const float4*)(p.x + ((size_t)(b0 + l15) * TLEN + 0) * 4);
      bf16x8 f = bfzero();
      f[0] = (__bf16)x0.x; f[1] = (__bf16)x0.y; f[2] = (__bf16)x0.z; f[3] = (__bf16)x0.w;
      xA0 = f;
      const float4 x1 = *(const float4*)(p.x + ((size_t)(b0 + l15) * TLEN + 1) * 4);
      bf16x8 g = bfzero();
      g[0] = (__bf16)x1.x; g[1] = (__bf16)x1.y; g[2] = (__bf16)x1.z; g[3] = (__bf16)x1.w;
      xB0 = g;
    }
  } else {
    // initial fill: need h_0, h_1 -> flag >= 2
    int v = 0, it = 0;
    do {
      if (lane == 0) v = __hip_atomic_load(&prodflag[srcf], __ATOMIC_ACQUIRE, AG);
      v = __shfl(v, 0);
      if (v >= 2) break;
      __builtin_amdgcn_s_sleep(4);
    } while (++it < SPIN_CAP);
    W = v;
    load_frag_pair(ring + (srcring + 0) * 1024, l15, quad, xA0, xA1);
    load_frag_pair(ring + (srcring + (1 & RM)) * 1024, l15, quad, xB0, xB1);
  }

  for (int t = 0; t < TLEN; t++) {
    // materialize last step's overlapped polls; issue fresh ones (lane0, fire&forget)
    if (L > 0) {
      int fm = __shfl(f_pend, 0);
      if (fm > W) W = fm;
      if (lane == 0) f_pend = __hip_atomic_load(&prodflag[srcf], __ATOMIC_RELAXED, AG);
    }
    if (L < 3) {
      int am = __shfl(a_pend, 0);
      if (am > ackW) ackW = am;
      if (lane == 0) a_pend = __hip_atomic_load(&ackflag[ownf], __ATOMIC_RELAXED, AG);
    }

    const int rb = t & 1, wb = rb ^ 1;
    // recurrent h fragments from LDS (swizzled)
    bf16x8 hf0, hf1;
    {
      int sg0 = quad ^ (l15 & 7);
      int sg1 = (4 + quad) ^ (l15 & 7);
      hf0 = *(const bf16x8*)&h_lds[rb * 1024 + l15 * 64 + sg0 * 8];
      hf1 = *(const bf16x8*)&h_lds[rb * 1024 + l15 * 64 + sg1 * 8];
    }

    f32x4 acc[4];
#pragma unroll
    for (int g = 0; g < 4; g++) { f32x4 a = {bias[g], bias[g], bias[g], bias[g]}; acc[g] = a; }
    if (L == 0) {
#pragma unroll
      for (int g = 0; g < 4; g++)
        acc[g] = __builtin_amdgcn_mfma_f32_16x16x32_bf16(xA0, wihf[g][0], acc[g], 0, 0, 0);
    } else {
#pragma unroll
      for (int g = 0; g < 4; g++) {
        acc[g] = __builtin_amdgcn_mfma_f32_16x16x32_bf16(xA0, wihf[g][0], acc[g], 0, 0, 0);
        acc[g] = __builtin_amdgcn_mfma_f32_16x16x32_bf16(xA1, wihf[g][1], acc[g], 0, 0, 0);
      }
    }
#pragma unroll
    for (int g = 0; g < 4; g++) {
      acc[g] = __builtin_amdgcn_mfma_f32_16x16x32_bf16(hf0, whhf[g][0], acc[g], 0, 0, 0);
      acc[g] = __builtin_amdgcn_mfma_f32_16x16x32_bf16(hf1, whhf[g][1], acc[g], 0, 0, 0);
    }

    // watermark check for the post-barrier prefetch (slot t+2 requires flag >= t+3)
    if (L > 0 && t + 2 < TLEN && W < t + 3) {
      int v = W, it = 0;
      do {
        if (lane == 0) v = __hip_atomic_load(&prodflag[srcf], __ATOMIC_ACQUIRE, AG);
        v = __shfl(v, 0);
        if (v >= t + 3) break;
        __builtin_amdgcn_s_sleep(4);
      } while (++it < SPIN_CAP);
      W = v;
    }
    // ring-reuse guard before overwriting slot (t & RM) post-barrier
    if (L < 3 && t >= R && ackW < t - R + GM) {
      int v = ackW, it = 0;
      do {
        if (lane == 0) v = __hip_atomic_load(&ackflag[ownf], __ATOMIC_ACQUIRE, AG);
        v = __shfl(v, 0);
        if (v >= t - R + GM) break;
        __builtin_amdgcn_s_sleep(4);
      } while (++it < SPIN_CAP);
      ackW = v;
    }

    // per-lane LSTM cell: lane holds (m = quad*4+r, col = w*16+l15) for all 4 gates
    const int col = w * 16 + l15;
    __bf16 hv[4]; unsigned hb[4];
#pragma unroll
    for (int r = 0; r < 4; r++) {
      float ig = fast_sigmoid(acc[0][r]);
      float fg = fast_sigmoid(acc[1][r]);
      float gg = fast_tanh(acc[2][r]);
      float og = fast_sigmoid(acc[3][r]);
      float c = fg * cst[r] + ig * gg;
      cst[r] = c;
      float h = og * fast_tanh(c);
      __bf16 hbf = (__bf16)h;
      hv[r] = hbf;
      union { __bf16 b; unsigned short s; } cv; cv.b = hbf;
      hb[r] = cv.s;
      int m  = quad * 4 + r;
      int sg = (col >> 3) ^ (m & 7);
      h_lds[wb * 1024 + m * 64 + sg * 8 + (col & 7)] = hbf;
    }

    __syncthreads();   // drains this wave's step-old vmcnt + LDS; publishes h tile

    // ---- post-barrier global work (fire & forget; drained by NEXT step's barrier) ----
    if (L < 3) {
      // all waves' h_{t-1} stores completed before this barrier -> flag=t is ordered
      if (tid == 0) __hip_atomic_store(&prodflag[ownf], t, __ATOMIC_RELAXED, AG);
      unsigned* dst = (unsigned*)(ring + (ownring + (size_t)(t & RM)) * 1024);
#pragma unroll
      for (int r = 0; r < 4; r++) {
        unsigned v = hb[r];
        unsigned o = (unsigned)__shfl_xor((int)v, 1);
        if ((lane & 1) == 0) {
          int m = quad * 4 + r;
          __hip_atomic_store(&dst[(m * 64 + col) >> 1], v | (o << 16), __ATOMIC_RELAXED, AG);
        }
      }
    }
    bf16x8 xN0 = bfzero(), xN1 = bfzero();
    if (t + 2 < TLEN) {
      if (L == 0) {
        if (quad == 0) {
          const float4 xv = *(const float4*)(p.x + ((size_t)(b0 + l15) * TLEN + (t + 2)) * 4);
          bf16x8 f = bfzero();
          f[0] = (__bf16)xv.x; f[1] = (__bf16)xv.y; f[2] = (__bf16)xv.z; f[3] = (__bf16)xv.w;
          xN0 = f;
        }
      } else {
        load_frag_pair(ring + (srcring + (size_t)((t + 2) & RM)) * 1024, l15, quad, xN0, xN1);
      }
    }
    if (L > 0 && tid == 0) __hip_atomic_store(&ackflag[srcf], t, __ATOMIC_RELAXED, AG);

    xA0 = xB0; xA1 = xB1; xB0 = xN0; xB1 = xN1;
  }

  // ---- FC head + softmax (layer-3 blocks; final h tile is in parity 0) ----
  if (L == 3) {
    for (int i = tid; i < 2048; i += 256) s_fc1w[i] = p.fc1w[i];
    if (tid < 32) s_fc1b[tid] = p.fc1b[tid];
    if (tid < 96) s_fc2w[tid] = p.fc2w[tid];
    if (tid < 3)  s_fc2b[tid] = p.fc2b[tid];
    __syncthreads();
    for (int pi = tid; pi < 512; pi += 256) {
      int m = pi >> 5, u = pi & 31;
      float s = s_fc1b[u];
      const float* wrow = &s_fc1w[u * 64];
#pragma unroll
      for (int k = 0; k < 64; k++) {
        int sg = (k >> 3) ^ (m & 7);
        s += (float)h_lds[m * 64 + sg * 8 + (k & 7)] * wrow[k];
      }
      s_z[m * 32 + u] = fmaxf(s, 0.f);
    }
    __syncthreads();
    if (tid < 16) {
      int m = tid;
      float lg[3];
#pragma unroll
      for (int v = 0; v < 3; v++) {
        float s = s_fc2b[v];
#pragma unroll
        for (int u = 0; u < 32; u++) s += s_z[m * 32 + u] * s_fc2w[v * 32 + u];
        lg[v] = s;
      }
      float mx = fmaxf(lg[0], fmaxf(lg[1], lg[2]));
      float e0 = __expf(lg[0] - mx), e1 = __expf(lg[1] - mx), e2 = __expf(lg[2] - mx);
      float inv = 1.f / (e0 + e1 + e2);
      float* o = p.out + (size_t)(b0 + m) * 3;
      o[0] = e0 * inv; o[1] = e1 * inv; o[2] = e2 * inv;
    }
  }
}

extern "C" void kernel_launch(void* const* d_in, const int* in_sizes, int n_in,
                              void* d_out, int out_size, void* d_ws, size_t ws_size,
                              hipStream_t stream)
{
  (void)in_sizes; (void)n_in; (void)out_size;
  Params p;
  p.x = (const float*)d_in[0];
  for (int l = 0; l < 4; l++) {
    p.wih[l] = (const float*)d_in[1 + 4 * l];
    p.whh[l] = (const float*)d_in[2 + 4 * l];
    p.bih[l] = (const float*)d_in[3 + 4 * l];
    p.bhh[l] = (const float*)d_in[4 + 4 * l];
  }
  p.fc1w = (const float*)d_in[17];
  p.fc1b = (const float*)d_in[18];
  p.fc2w = (const float*)d_in[19];
  p.fc2b = (const float*)d_in[20];
  p.out = (float*)d_out;
  p.ws  = (char*)d_ws;

  // ring: 3 boundaries x 64 chunks x R slots x 2KB = R * 384KB (+64KB counters)
  const size_t slotbytes = 3ull * NCH * 2048;
  const size_t avail = (ws_size > 65536) ? (ws_size - 65536) : 0;
  int R = 4;
  while (R < 16 && (size_t)(R * 2) * slotbytes <= avail) R <<= 1;
  p.R = R; p.Rmask = R - 1;
  p.guard = (R >= 8) ? 2 : 0;   // reuse-guard margin; R=4 runs tight-lockstep but correct

  hipLaunchKernelGGL(lstm_ring, dim3(256), dim3(256), 0, stream, p);
}

// Round 4
// 924.162 us; speedup vs baseline: 4696.6474x; 4696.6474x over previous
//
#include <hip/hip_runtime.h>

// 4-layer LSTM (B=1024,T=512,H=64,G=256) + FC head.
// 64 blocks x 1024 threads: block = 16-row batch chunk; wave-group (4 waves) = layer.
// Layers pipelined INSIDE the block (skew 1 superstep/layer); handoff via double-buffered
// swizzled LDS tiles + one __syncthreads per superstep. No cross-block sync, no d_ws.
//
// Round-4 changes vs round 2:
//  * __launch_bounds__(1024) only -- round 2's (1024,4) capped arch VGPRs at 64 and the
//    compiler bounced the 64 weight VGPRs through AGPRs (v_accvgpr VALU traffic, ~2x cell cost).
//  * Uniform K=128 concat layout: tiles[5] = [x | h_L0 | h_L1 | h_L2 | h_L3]; layer L reads
//    input tile L and own tile L+1, weights wf[gate][4 chunks] = [Wih(k0..63) | Whh(k0..63)].
//    Layer 0's x tile has k>=4 zeroed once at init; wave 0 of layer 0 refreshes x_{t+1} each step.
// bf16 MFMA 16x16x32, fp32 accum, c-state in registers.

#define TLEN 512
#define NCH  64

typedef __bf16 bf16x8 __attribute__((ext_vector_type(8)));
typedef float  f32x4  __attribute__((ext_vector_type(4)));

struct Params {
  const float* x;
  const float* wih[4]; const float* whh[4];
  const float* bih[4]; const float* bhh[4];
  const float* fc1w; const float* fc1b;
  const float* fc2w; const float* fc2b;
  float* out;
};

__device__ __forceinline__ bf16x8 bfzero() {
  union { unsigned long long u[2]; bf16x8 v; } z; z.u[0] = 0ull; z.u[1] = 0ull; return z.v;
}
__device__ __forceinline__ float fast_sigmoid(float x) {
  return __builtin_amdgcn_rcpf(1.f + __expf(-x));
}
__device__ __forceinline__ float fast_tanh(float x) {
  float e = __expf(2.f * x);
  return 1.f - 2.f * __builtin_amdgcn_rcpf(e + 1.f);
}

__global__ __launch_bounds__(1024) void lstm_fused(Params p)
{
  const int chunk = blockIdx.x;      // 16-row batch chunk
  const int b0   = chunk * 16;
  const int tid  = threadIdx.x;
  const int wave = tid >> 6;
  const int L    = wave >> 2;        // layer = wave group
  const int w    = wave & 3;         // cols [16w,16w+16) of each gate
  const int lane = tid & 63;
  const int quad = lane >> 4;
  const int l15  = lane & 15;

  // tiles: [parity][0..4] ; tile 0 = x (K-padded), tile L+1 = layer L's h. 16x64 bf16, swizzled.
  __shared__ __bf16 tiles[2][5][16 * 64];
  __shared__ float  s_fc1w[2048];
  __shared__ float  s_z[512];
  __shared__ float  s_fc1b[32];
  __shared__ float  s_fc2w[96];
  __shared__ float  s_fc2b[3];

  // ---- weight fragments: wf[gate][chunk], chunks 0-1 = Wih (K 0..63), 2-3 = Whh (K 0..63) ----
  bf16x8 wf[4][4];
  float  bias[4];
  {
    const float* wih = p.wih[L];
    const float* whh = p.whh[L];
    const float* bih = p.bih[L];
    const float* bhh = p.bhh[L];
#pragma unroll
    for (int g = 0; g < 4; g++) {
      int n = g * 64 + w * 16 + l15;   // B-frag: lane&15 = n, k = 32*chunk + quad*8 + j
      bias[g] = bih[n] + bhh[n];
      if (L == 0) {                    // w_ih_0 is (256,4): K-pad to 64 with zeros
        bf16x8 f = bfzero();
        if (quad == 0) {
#pragma unroll
          for (int j = 0; j < 4; j++) f[j] = (__bf16)wih[n * 4 + j];
        }
        wf[g][0] = f; wf[g][1] = bfzero();
      } else {
#pragma unroll
        for (int q = 0; q < 2; q++) {
          const float* s = wih + n * 64 + q * 32 + quad * 8;
          bf16x8 f;
#pragma unroll
          for (int j = 0; j < 8; j++) f[j] = (__bf16)s[j];
          wf[g][q] = f;
        }
      }
#pragma unroll
      for (int q = 0; q < 2; q++) {
        const float* s = whh + n * 64 + q * 32 + quad * 8;
        bf16x8 f;
#pragma unroll
        for (int j = 0; j < 8; j++) f[j] = (__bf16)s[j];
        wf[g][2 + q] = f;
      }
    }
  }

  { // zero all tiles, both parities (x tile padding + zero initial h/pipeline-fill reads)
    int* ti = (int*)tiles;
    for (int i = tid; i < 5120; i += 1024) ti[i] = 0;
  }
  float cst[4] = {0.f, 0.f, 0.f, 0.f};

  // x for t=0 goes into tiles[0][0]; x row r at k=0..3 lives at r*64 + (r&7)*8 + k (sg = r&7).
  if (wave == 0 && quad == 0) {
    const float4 xv = *(const float4*)(p.x + ((size_t)(b0 + l15) * TLEN) * 4);
    __bf16 v[4] = {(__bf16)xv.x, (__bf16)xv.y, (__bf16)xv.z, (__bf16)xv.w};
    *(float2*)&tiles[0][0][l15 * 64 + (l15 & 7) * 8] = *(float2*)v;
  }
  __syncthreads();

  for (int s = 0; s < TLEN + 3; s++) {
    const int t  = s - L;
    const int pr = s & 1;
    const int pw = pr ^ 1;

    if ((unsigned)t < (unsigned)TLEN) {
      // A-frags (lane&15 = row, k = 32q + quad*8 + j), swizzled reads
      const __bf16* in  = tiles[pr][L];
      const __bf16* own = tiles[pr][L + 1];
      const int sg0 = quad ^ (l15 & 7);
      const int sg1 = (4 + quad) ^ (l15 & 7);
      bf16x8 xf0 = *(const bf16x8*)&in [l15 * 64 + sg0 * 8];
      bf16x8 xf1 = *(const bf16x8*)&in [l15 * 64 + sg1 * 8];
      bf16x8 hf0 = *(const bf16x8*)&own[l15 * 64 + sg0 * 8];
      bf16x8 hf1 = *(const bf16x8*)&own[l15 * 64 + sg1 * 8];

      f32x4 acc[4];
#pragma unroll
      for (int g = 0; g < 4; g++) { f32x4 a = {bias[g], bias[g], bias[g], bias[g]}; acc[g] = a; }
#pragma unroll
      for (int g = 0; g < 4; g++) {
        acc[g] = __builtin_amdgcn_mfma_f32_16x16x32_bf16(xf0, wf[g][0], acc[g], 0, 0, 0);
        acc[g] = __builtin_amdgcn_mfma_f32_16x16x32_bf16(xf1, wf[g][1], acc[g], 0, 0, 0);
        acc[g] = __builtin_amdgcn_mfma_f32_16x16x32_bf16(hf0, wf[g][2], acc[g], 0, 0, 0);
        acc[g] = __builtin_amdgcn_mfma_f32_16x16x32_bf16(hf1, wf[g][3], acc[g], 0, 0, 0);
      }

      // refresh x tile for t+1 while MFMAs are in flight (layer 0, wave 0 only)
      if (wave == 0 && quad == 0 && t + 1 < TLEN) {
        const float4 xv = *(const float4*)(p.x + ((size_t)(b0 + l15) * TLEN + (t + 1)) * 4);
        __bf16 v[4] = {(__bf16)xv.x, (__bf16)xv.y, (__bf16)xv.z, (__bf16)xv.w};
        *(float2*)&tiles[pw][0][l15 * 64 + (l15 & 7) * 8] = *(float2*)v;
      }

      // per-lane cell: lane holds (row m = quad*4+r, col = w*16+l15) for all 4 gates
      const int col = w * 16 + l15;
      __bf16* dst = tiles[pw][L + 1];
#pragma unroll
      for (int r = 0; r < 4; r++) {
        float ig = fast_sigmoid(acc[0][r]);
        float fg = fast_sigmoid(acc[1][r]);
        float gg = fast_tanh(acc[2][r]);
        float og = fast_sigmoid(acc[3][r]);
        float c = fg * cst[r] + ig * gg;
        cst[r] = c;
        float h = og * fast_tanh(c);
        int m  = quad * 4 + r;
        int sg = (col >> 3) ^ (m & 7);
        dst[m * 64 + sg * 8 + (col & 7)] = (__bf16)h;
      }
    }

    __syncthreads();   // publish h tiles (and x tile) to the next superstep
  }

  // ---- FC head + softmax. h(t=511, layer 3) written at s=514 -> parity (514&1)^1 = 1.
  for (int i = tid; i < 2048; i += 1024) s_fc1w[i] = p.fc1w[i];
  if (tid < 32) s_fc1b[tid] = p.fc1b[tid];
  if (tid < 96) s_fc2w[tid] = p.fc2w[tid];
  if (tid < 3)  s_fc2b[tid] = p.fc2b[tid];
  __syncthreads();
  if (tid < 512) {
    int m = tid >> 5, u = tid & 31;
    float sacc = s_fc1b[u];
    const float* wrow = &s_fc1w[u * 64];
    const __bf16* hfin = tiles[1][4];
#pragma unroll
    for (int k = 0; k < 64; k++) {
      int sg = (k >> 3) ^ (m & 7);
      sacc += (float)hfin[m * 64 + sg * 8 + (k & 7)] * wrow[k];
    }
    s_z[m * 32 + u] = fmaxf(sacc, 0.f);
  }
  __syncthreads();
  if (tid < 16) {
    int m = tid;
    float lg[3];
#pragma unroll
    for (int v = 0; v < 3; v++) {
      float sv = s_fc2b[v];
#pragma unroll
      for (int u = 0; u < 32; u++) sv += s_z[m * 32 + u] * s_fc2w[v * 32 + u];
      lg[v] = sv;
    }
    float mx = fmaxf(lg[0], fmaxf(lg[1], lg[2]));
    float e0 = __expf(lg[0] - mx), e1 = __expf(lg[1] - mx), e2 = __expf(lg[2] - mx);
    float inv = 1.f / (e0 + e1 + e2);
    float* o = p.out + (size_t)(b0 + m) * 3;
    o[0] = e0 * inv; o[1] = e1 * inv; o[2] = e2 * inv;
  }
}

extern "C" void kernel_launch(void* const* d_in, const int* in_sizes, int n_in,
                              void* d_out, int out_size, void* d_ws, size_t ws_size,
                              hipStream_t stream)
{
  (void)in_sizes; (void)n_in; (void)out_size; (void)d_ws; (void)ws_size;
  Params p;
  p.x = (const float*)d_in[0];
  for (int l = 0; l < 4; l++) {
    p.wih[l] = (const float*)d_in[1 + 4 * l];
    p.whh[l] = (const float*)d_in[2 + 4 * l];
    p.bih[l] = (const float*)d_in[3 + 4 * l];
    p.bhh[l] = (const float*)d_in[4 + 4 * l];
  }
  p.fc1w = (const float*)d_in[17];
  p.fc1b = (const float*)d_in[18];
  p.fc2w = (const float*)d_in[19];
  p.fc2b = (const float*)d_in[20];
  p.out = (float*)d_out;

  hipLaunchKernelGGL(lstm_fused, dim3(NCH), dim3(1024), 0, stream, p);
}